// Round 5
// baseline (1215.773 us; speedup 1.0000x reference)
//
#include <hip/hip_runtime.h>
#include <math.h>

#define NB 32
#define NL 512
#define ND 384
#define NH 6
#define NCP 52
#define NC 50

// XOR swizzle for [row][64] f32 LDS tiles: permutes 16B chunks, keeps 4-chunks contiguous.
__device__ __forceinline__ int swz(int row, int k) {
    return k ^ (((row >> 2) & 7) << 2);
}

// ---------------- zero accumulators ----------------
__global__ void zero_kernel(float4* zb) {
    int idx = blockIdx.x * 256 + threadIdx.x;
    float4 z; z.x = 0.f; z.y = 0.f; z.z = 0.f; z.w = 0.f;
    for (int i = idx; i < 25000; i += 64 * 256) zb[i] = z;
}

// ---------------- embedding + tfidf weight + q2 ----------------
__global__ __launch_bounds__(384) void embed_kernel(
    const int* __restrict__ tids, const int* __restrict__ TFs, const int* __restrict__ DFs,
    const float* __restrict__ emb, float* __restrict__ hw, float* __restrict__ q2) {
    int t = threadIdx.x;
    int bl = blockIdx.x;               // 0..B*L-1
    int b = bl >> 9, l = bl & 511;
    int tid = tids[bl];
    float tf = log1pf(fminf((float)TFs[bl], 20.f));
    float idf = 1.f / logf((float)DFs[bl] + 2.f);
    float wt = tf * idf;
    float hv = emb[(size_t)tid * ND + t] * wt;
    int hh = t >> 6, dd = t & 63;
    hw[((size_t)(b * NH + hh) * NL + l) * 64 + dd] = hv;
    float q = hv * hv;
    for (int off = 1; off < 64; off <<= 1) q += __shfl_xor(q, off);
    if (dd == 0) q2[(b * NH + hh) * NL + l] = q;
}

// ---------------- pairwise distance + BN stats (per head) ----------------
// 64-row i-tile, per-jt 64x64 B tile. LDS = 33 KB -> multi-block residency.
__global__ __launch_bounds__(256, 2) void dist_stats_kernel(
    const float* __restrict__ hw, const float* __restrict__ q2g,
    float* __restrict__ co, double* __restrict__ stats, int h) {
    __shared__ float As[64 * 64];
    __shared__ float Bs[64 * 64];
    __shared__ float q2i[64], q2j[64];
    __shared__ float red[8];
    int t = threadIdx.x;
    int b = blockIdx.x >> 3;
    int i0 = (blockIdx.x & 7) << 6;
    const float* hb = hw + (size_t)(b * NH + h) * (NL * 64);
    const float* q2b = q2g + (b * NH + h) * NL;
#pragma unroll
    for (int it = 0; it < 4; ++it) {
        int f4i = t + (it << 8);
        int row = f4i >> 4, kc = (f4i & 15) << 2;
        float4 v = *(const float4*)(hb + (size_t)(i0 + row) * 64 + kc);
        *(float4*)(As + row * 64 + swz(row, kc)) = v;
    }
    if (t < 64) q2i[t] = q2b[i0 + t];
    int tx = t & 15, ty = t >> 4;
    float lsum = 0.f, lss = 0.f;
    for (int jt = 0; jt < 8; ++jt) {
        __syncthreads();               // previous Bs users done
#pragma unroll
        for (int it = 0; it < 4; ++it) {
            int f4i = t + (it << 8);
            int row = f4i >> 4, kc = (f4i & 15) << 2;
            float4 v = *(const float4*)(hb + (size_t)((jt << 6) + row) * 64 + kc);
            *(float4*)(Bs + row * 64 + swz(row, kc)) = v;
        }
        if (t < 64) q2j[t] = q2b[(jt << 6) + t];
        __syncthreads();
        float acc[4][4] = {};
        for (int kc = 0; kc < 64; kc += 4) {
            float4 a[4], bb[4];
#pragma unroll
            for (int r = 0; r < 4; ++r)
                a[r] = *(const float4*)(As + (ty * 4 + r) * 64 + swz(ty * 4 + r, kc));
#pragma unroll
            for (int c = 0; c < 4; ++c)
                bb[c] = *(const float4*)(Bs + (tx * 4 + c) * 64 + swz(tx * 4 + c, kc));
#pragma unroll
            for (int r = 0; r < 4; ++r)
#pragma unroll
                for (int c = 0; c < 4; ++c)
                    acc[r][c] += a[r].x * bb[c].x + a[r].y * bb[c].y + a[r].z * bb[c].z + a[r].w * bb[c].w;
        }
#pragma unroll
        for (int r = 0; r < 4; ++r) {
            int i = ty * 4 + r;
            float q2iv = q2i[i];
            float4 o;
            float d0 = q2iv + q2j[tx * 4 + 0] - 2.f * acc[r][0];
            float d1 = q2iv + q2j[tx * 4 + 1] - 2.f * acc[r][1];
            float d2 = q2iv + q2j[tx * 4 + 2] - 2.f * acc[r][2];
            float d3 = q2iv + q2j[tx * 4 + 3] - 2.f * acc[r][3];
            o.x = sqrtf(fmaxf(d0, 0.f) + 1e-12f);
            o.y = sqrtf(fmaxf(d1, 0.f) + 1e-12f);
            o.z = sqrtf(fmaxf(d2, 0.f) + 1e-12f);
            o.w = sqrtf(fmaxf(d3, 0.f) + 1e-12f);
            lsum += o.x + o.y + o.z + o.w;
            lss += o.x * o.x + o.y * o.y + o.z * o.z + o.w * o.w;
            *(float4*)(co + ((size_t)(b << 9) + i0 + i) * NL + (jt << 6) + (tx << 2)) = o;
        }
    }
    for (int off = 1; off < 64; off <<= 1) {
        lsum += __shfl_xor(lsum, off);
        lss += __shfl_xor(lss, off);
    }
    __syncthreads();
    if ((t & 63) == 0) { red[(t >> 6) * 2] = lsum; red[(t >> 6) * 2 + 1] = lss; }
    __syncthreads();
    if (t == 0) {
        float s = 0.f, ss = 0.f;
        for (int w = 0; w < 4; ++w) { s += red[w * 2]; ss += red[w * 2 + 1]; }
        atomicAdd(&stats[h * 2], (double)s);
        atomicAdd(&stats[h * 2 + 1], (double)ss);
    }
}

// ---------------- finalize BN affine for head h ----------------
__global__ void fin_kernel(const double* __restrict__ stats, const float* __restrict__ gamma,
                           const float* __restrict__ beta, float* __restrict__ bnab, int h) {
    if (threadIdx.x == 0) {
        double n = (double)NB * NL * NL;
        double mu = stats[h * 2] / n;
        double var = stats[h * 2 + 1] / n - mu * mu;
        double inv = 1.0 / sqrt(var + 1e-5);
        double a = (double)gamma[h] * inv;
        bnab[h * 2] = (float)a;
        bnab[h * 2 + 1] = (float)((double)beta[h] - mu * a);
    }
}

// ---------------- fused softmax (no max pass) + PV + colsum (per head) ----------------
// BN standardizes scores -> exp() is f32-safe without max subtraction (identical result).
// Phase 1: sweep co once, e=exp() -> LDS tile, accumulate unnormalized PV + row sums l.
// Phase 2: re-sweep co (L2-hot, block re-reads its own 128 KB) for colsum scaled by 1/l.
__global__ __launch_bounds__(256, 2) void softpv_kernel(
    const float* __restrict__ co, const float* __restrict__ hw, const int* __restrict__ tids,
    const float* __restrict__ bnab, float* __restrict__ Vcat, float* __restrict__ colsum, int h) {
    __shared__ float Es[64 * 64];
    __shared__ float Vs[64 * 64];
    __shared__ float csw[4][512];
    __shared__ float rl[64];
    __shared__ int padi[64];
    int t = threadIdx.x;
    int b = blockIdx.x >> 3;
    int i0 = (blockIdx.x & 7) << 6;
    float a = bnab[h * 2], bb = bnab[h * 2 + 1];
    if (t < 64) padi[t] = (tids[(b << 9) + i0 + t] != 0) ? 1 : 0;
    for (int k = t; k < 2048; k += 256) ((float*)csw)[k] = 0.f;
    int tx = t & 15, ty = t >> 4;
    const float* hb = hw + (size_t)(b * NH + h) * (NL * 64);
    float U[4][4] = {};
    float lac[4] = {0.f, 0.f, 0.f, 0.f};
    __syncthreads();
    for (int jt = 0; jt < 8; ++jt) {
        // stage V tile
#pragma unroll
        for (int it = 0; it < 4; ++it) {
            int f4i = t + (it << 8);
            int row = f4i >> 4, kc = (f4i & 15) << 2;
            float4 v = *(const float4*)(hb + (size_t)((jt << 6) + row) * 64 + kc);
            *(float4*)(Vs + row * 64 + swz(row, kc)) = v;
        }
        // e = exp(masked affine), store to Es, accumulate row sums
        int4 tj = *(const int4*)(tids + (b << 9) + (jt << 6) + (tx << 2));
#pragma unroll
        for (int r = 0; r < 4; ++r) {
            int i = ty * 4 + r;
            bool pi = padi[i] != 0;
            float4 v = *(const float4*)(co + ((size_t)(b << 9) + i0 + i) * NL + (jt << 6) + (tx << 2));
            float4 e;
            e.x = __expf((pi && tj.x != 0) ? a * v.x + bb : 0.f);
            e.y = __expf((pi && tj.y != 0) ? a * v.y + bb : 0.f);
            e.z = __expf((pi && tj.z != 0) ? a * v.z + bb : 0.f);
            e.w = __expf((pi && tj.w != 0) ? a * v.w + bb : 0.f);
            lac[r] += e.x + e.y + e.z + e.w;
            *(float4*)(Es + i * 64 + swz(i, tx << 2)) = e;
        }
        __syncthreads();
        // unnormalized PV accumulate
        for (int jc = 0; jc < 64; jc += 4) {
            float4 pa[4], vb[4];
#pragma unroll
            for (int r = 0; r < 4; ++r)
                pa[r] = *(const float4*)(Es + (ty * 4 + r) * 64 + swz(ty * 4 + r, jc));
#pragma unroll
            for (int u = 0; u < 4; ++u)
                vb[u] = *(const float4*)(Vs + (jc + u) * 64 + swz(jc + u, tx << 2));
#pragma unroll
            for (int r = 0; r < 4; ++r) {
                U[r][0] += pa[r].x * vb[0].x + pa[r].y * vb[1].x + pa[r].z * vb[2].x + pa[r].w * vb[3].x;
                U[r][1] += pa[r].x * vb[0].y + pa[r].y * vb[1].y + pa[r].z * vb[2].y + pa[r].w * vb[3].y;
                U[r][2] += pa[r].x * vb[0].z + pa[r].y * vb[1].z + pa[r].z * vb[2].z + pa[r].w * vb[3].z;
                U[r][3] += pa[r].x * vb[0].w + pa[r].y * vb[1].w + pa[r].z * vb[2].w + pa[r].w * vb[3].w;
            }
        }
        __syncthreads();
    }
    // row sums: reduce over tx lanes (bits 0..3), then 1/l
#pragma unroll
    for (int r = 0; r < 4; ++r) {
        float s = lac[r];
        s += __shfl_xor(s, 1); s += __shfl_xor(s, 2);
        s += __shfl_xor(s, 4); s += __shfl_xor(s, 8);
        if (tx == 0) rl[ty * 4 + r] = 1.f / s;
    }
    __syncthreads();
    // scale + write Vcat
#pragma unroll
    for (int r = 0; r < 4; ++r) {
        int i = ty * 4 + r;
        float rr = rl[i];
        float4 o;
        o.x = U[r][0] * rr; o.y = U[r][1] * rr; o.z = U[r][2] * rr; o.w = U[r][3] * rr;
        *(float4*)(Vcat + ((size_t)(b << 9) + i0 + i) * ND + h * 64 + (tx << 2)) = o;
    }
    // phase 2: colsum (re-read co, L2-hot)
    int wv = t >> 6;
    for (int jt = 0; jt < 8; ++jt) {
        int4 tj = *(const int4*)(tids + (b << 9) + (jt << 6) + (tx << 2));
        float cp0 = 0.f, cp1 = 0.f, cp2 = 0.f, cp3 = 0.f;
#pragma unroll
        for (int r = 0; r < 4; ++r) {
            int i = ty * 4 + r;
            bool pi = padi[i] != 0;
            float rr = rl[i];
            float4 v = *(const float4*)(co + ((size_t)(b << 9) + i0 + i) * NL + (jt << 6) + (tx << 2));
            cp0 += __expf((pi && tj.x != 0) ? a * v.x + bb : 0.f) * rr;
            cp1 += __expf((pi && tj.y != 0) ? a * v.y + bb : 0.f) * rr;
            cp2 += __expf((pi && tj.z != 0) ? a * v.z + bb : 0.f) * rr;
            cp3 += __expf((pi && tj.w != 0) ? a * v.w + bb : 0.f) * rr;
        }
        cp0 += __shfl_xor(cp0, 16); cp0 += __shfl_xor(cp0, 32);
        cp1 += __shfl_xor(cp1, 16); cp1 += __shfl_xor(cp1, 32);
        cp2 += __shfl_xor(cp2, 16); cp2 += __shfl_xor(cp2, 32);
        cp3 += __shfl_xor(cp3, 16); cp3 += __shfl_xor(cp3, 32);
        if ((t & 48) == 0) {       // one ty-group per wave holds the wave partial
            int j = (jt << 6) + (tx << 2);
            csw[wv][j + 0] += cp0;
            csw[wv][j + 1] += cp1;
            csw[wv][j + 2] += cp2;
            csw[wv][j + 3] += cp3;
        }
    }
    __syncthreads();
    for (int k = t; k < 512; k += 256) {
        float s = csw[0][k] + csw[1][k] + csw[2][k] + csw[3][k];
        atomicAdd(&colsum[(size_t)(b * NH + h) * NL + k], s);
    }
}

// ---------------- token-weight softmax w[b,l] ----------------
__global__ __launch_bounds__(512) void wk_kernel(
    const int* __restrict__ tids, const float* __restrict__ colsum, float* __restrict__ wvec) {
    __shared__ float red[8];
    __shared__ int redi[8];
    int b = blockIdx.x, l = threadIdx.x;
    int lane = l & 63, wv = l >> 6;
    int padv = (tids[(b << 9) + l] != 0) ? 1 : 0;
    int cnt = padv;
    for (int off = 1; off < 64; off <<= 1) cnt += __shfl_xor(cnt, off);
    if (lane == 0) redi[wv] = cnt;
    __syncthreads();
    int ds = 0;
    for (int k = 0; k < 8; ++k) ds += redi[k];
    if (ds < 1) ds = 1;
    float cs = 0.f;
    for (int hh = 0; hh < NH; ++hh) cs += colsum[(size_t)(b * NH + hh) * NL + l];
    float x = padv ? cs / (6.f * (float)ds) : -INFINITY;
    float m = x;
    for (int off = 1; off < 64; off <<= 1) m = fmaxf(m, __shfl_xor(m, off));
    if (lane == 0) red[wv] = m;
    __syncthreads();
    float bm = red[0];
    for (int k = 1; k < 8; ++k) bm = fmaxf(bm, red[k]);
    float e = padv ? __expf(x - bm) : 0.f;
    float se = e;
    for (int off = 1; off < 64; off <<= 1) se += __shfl_xor(se, off);
    __syncthreads();
    if (lane == 0) red[wv] = se;
    __syncthreads();
    float total = 0.f;
    for (int k = 0; k < 8; ++k) total += red[k];
    wvec[(b << 9) + l] = (total > 0.f) ? e / total : 0.f;
}

// ---------------- fc + per-token softmax + weighted sum ----------------
__global__ __launch_bounds__(256) void logits_kernel(
    const float* __restrict__ Vcat, const float* __restrict__ fcw, const float* __restrict__ fcb,
    const float* __restrict__ wvec, float* __restrict__ lacc) {
    __shared__ float red[4][64];
    int t = threadIdx.x;
    int wv = t >> 6, lane = t & 63;
    int tok0 = (blockIdx.x * 4 + wv) * 4;    // 16 consecutive tokens per block
    int b = tok0 >> 9;                       // all 16 in the same batch row
    int wrow = (lane < NCP) ? lane : (NCP - 1);
    const float* wp = fcw + wrow * ND;
    const float* vp = Vcat + (size_t)tok0 * ND;
    float acc0 = 0.f, acc1 = 0.f, acc2 = 0.f, acc3 = 0.f;
#pragma unroll 2
    for (int kc = 0; kc < ND; kc += 4) {
        float4 w4 = *(const float4*)(wp + kc);
        float4 v0 = *(const float4*)(vp + kc);
        float4 v1 = *(const float4*)(vp + ND + kc);
        float4 v2 = *(const float4*)(vp + 2 * ND + kc);
        float4 v3 = *(const float4*)(vp + 3 * ND + kc);
        acc0 += v0.x * w4.x + v0.y * w4.y + v0.z * w4.z + v0.w * w4.w;
        acc1 += v1.x * w4.x + v1.y * w4.y + v1.z * w4.z + v1.w * w4.w;
        acc2 += v2.x * w4.x + v2.y * w4.y + v2.z * w4.z + v2.w * w4.w;
        acc3 += v3.x * w4.x + v3.y * w4.y + v3.z * w4.z + v3.w * w4.w;
    }
    float bias = fcb[wrow];
    float g[4] = {acc0 + bias, acc1 + bias, acc2 + bias, acc3 + bias};
    float lsum = 0.f;
#pragma unroll
    for (int u = 0; u < 4; ++u) {
        float gm = (lane < NCP) ? g[u] : -INFINITY;
        float m = gm;
        for (int off = 1; off < 64; off <<= 1) m = fmaxf(m, __shfl_xor(m, off));
        float e = (lane < NCP) ? __expf(g[u] - m) : 0.f;
        float s = e;
        for (int off = 1; off < 64; off <<= 1) s += __shfl_xor(s, off);
        lsum += (e / s) * wvec[tok0 + u];
    }
    red[wv][lane] = lsum;
    __syncthreads();
    if (wv == 0) {
        float tot = red[0][lane] + red[1][lane] + red[2][lane] + red[3][lane];
        if (lane < NCP) atomicAdd(&lacc[b * NCP + lane], tot);
    }
}

// ---------------- final softmax over first 50 ----------------
__global__ __launch_bounds__(64) void final_kernel(const float* __restrict__ lacc, float* __restrict__ out) {
    int b = blockIdx.x, lane = threadIdx.x;
    float x = (lane < NC) ? lacc[b * NCP + lane] : -INFINITY;
    float m = x;
    for (int off = 1; off < 64; off <<= 1) m = fmaxf(m, __shfl_xor(m, off));
    float e = (lane < NC) ? __expf(x - m) : 0.f;
    float s = e;
    for (int off = 1; off < 64; off <<= 1) s += __shfl_xor(s, off);
    if (lane < NC) out[b * NC + lane] = e / s;
}

extern "C" void kernel_launch(void* const* d_in, const int* in_sizes, int n_in,
                              void* d_out, int out_size, void* d_ws, size_t ws_size,
                              hipStream_t stream) {
    const int* tids = (const int*)d_in[0];
    const int* TFs = (const int*)d_in[1];
    const int* DFs = (const int*)d_in[2];
    const float* emb = (const float*)d_in[3];
    const float* gamma = (const float*)d_in[4];
    const float* beta = (const float*)d_in[5];
    const float* fcw = (const float*)d_in[6];
    const float* fcb = (const float*)d_in[7];
    float* out = (float*)d_out;

    char* ws = (char*)d_ws;
    float* hw = (float*)ws;                              // 25,165,824 B
    float* q2 = (float*)(ws + 25165824);                 //    393,216 B
    float* co = (float*)(ws + 25559040);                 // 33,554,432 B (per-head reuse)
    float* Vcat = (float*)(ws + 59113472);               // 25,165,824 B
    char* zbase = ws + 84279296;                         //    400,000 B zero region
    double* stats = (double*)zbase;                      // 12 doubles (pad 128)
    float* colsum = (float*)(zbase + 128);               //    393,216 B
    float* lacc = (float*)(zbase + 128 + 393216);        //      6,656 B
    float* bnab = (float*)(ws + 84679296);               //         48 B
    float* wvec = (float*)(ws + 84679360);               //     65,536 B

    zero_kernel<<<64, 256, 0, stream>>>((float4*)zbase);
    embed_kernel<<<NB * NL, ND, 0, stream>>>(tids, TFs, DFs, emb, hw, q2);
    for (int h = 0; h < NH; ++h) {
        dist_stats_kernel<<<NB * 8, 256, 0, stream>>>(hw, q2, co, stats, h);
        fin_kernel<<<1, 64, 0, stream>>>(stats, gamma, beta, bnab, h);
        softpv_kernel<<<NB * 8, 256, 0, stream>>>(co, hw, tids, bnab, Vcat, colsum, h);
    }
    wk_kernel<<<NB, 512, 0, stream>>>(tids, colsum, wvec);
    logits_kernel<<<NB * 4, 256, 0, stream>>>(Vcat, fcw, fcb, wvec, lacc);
    final_kernel<<<NB, 64, 0, stream>>>(lacc, out);
}

// Round 7
// 771.223 us; speedup vs baseline: 1.5764x; 1.5764x over previous
//
#include <hip/hip_runtime.h>
#include <math.h>

#define NB 32
#define NL 512
#define ND 384
#define NH 6
#define NCP 52
#define NC 50
#define NBH (NB * NH)   // 192 head-batches

// XOR swizzle for [row][64] f32 LDS tiles: permutes 16B chunks, keeps 4-chunks contiguous.
__device__ __forceinline__ int swz(int row, int k) {
    return k ^ (((row >> 2) & 7) << 2);
}

// XCD-chunked block decode: grid 1536 = 8 XCDs x 192; consecutive sid share (b,h)
// so one XCD's L2 holds that (b,h)'s hw slice across its 8 i0-tiles.
__device__ __forceinline__ void decode_blk(int orig, int& bh, int& i0) {
    int sid = (orig & 7) * 192 + (orig >> 3);
    i0 = (sid & 7) << 6;
    bh = sid >> 3;                    // b * NH + h
}

// stage a 64x64 f32 tile (row-major, ld=64) into swizzled LDS; 256 threads
__device__ __forceinline__ void stage_tile(const float* __restrict__ src, float* dst, int t) {
#pragma unroll
    for (int it = 0; it < 4; ++it) {
        int f4i = t + (it << 8);
        int row = f4i >> 4, kc = (f4i & 15) << 2;
        float4 v = *(const float4*)(src + (size_t)row * 64 + kc);
        *(float4*)(dst + row * 64 + swz(row, kc)) = v;
    }
}

// 64x64 pairwise-distance tile from swizzled As/Bs; IDENTICAL FP ordering everywhere
// so pass B and pass C recompute bit-identical values.
__device__ __forceinline__ void dist_tile(const float* As, const float* Bs,
                                          const float* q2i, const float* q2j,
                                          int tx, int ty, float co[4][4]) {
    float acc[4][4] = {};
    for (int kc = 0; kc < 64; kc += 4) {
        float4 a[4], bb[4];
#pragma unroll
        for (int r = 0; r < 4; ++r)
            a[r] = *(const float4*)(As + (ty * 4 + r) * 64 + swz(ty * 4 + r, kc));
#pragma unroll
        for (int c = 0; c < 4; ++c)
            bb[c] = *(const float4*)(Bs + (tx * 4 + c) * 64 + swz(tx * 4 + c, kc));
#pragma unroll
        for (int r = 0; r < 4; ++r)
#pragma unroll
            for (int c = 0; c < 4; ++c)
                acc[r][c] += a[r].x * bb[c].x + a[r].y * bb[c].y + a[r].z * bb[c].z + a[r].w * bb[c].w;
    }
#pragma unroll
    for (int r = 0; r < 4; ++r)
#pragma unroll
        for (int c = 0; c < 4; ++c) {
            float d = q2i[ty * 4 + r] + q2j[tx * 4 + c] - 2.f * acc[r][c];
            co[r][c] = sqrtf(fmaxf(d, 0.f) + 1e-12f);
        }
}

// ---------------- zero accumulators ----------------
__global__ void zero_kernel(float4* zb) {
    int idx = blockIdx.x * 256 + threadIdx.x;
    float4 z; z.x = 0.f; z.y = 0.f; z.z = 0.f; z.w = 0.f;
    for (int i = idx; i < 25000; i += 64 * 256) zb[i] = z;
}

// ---------------- embedding + tfidf weight + q2 ----------------
__global__ __launch_bounds__(384) void embed_kernel(
    const int* __restrict__ tids, const int* __restrict__ TFs, const int* __restrict__ DFs,
    const float* __restrict__ emb, float* __restrict__ hw, float* __restrict__ q2) {
    int t = threadIdx.x;
    int bl = blockIdx.x;               // 0..B*L-1
    int b = bl >> 9, l = bl & 511;
    int tid = tids[bl];
    float tf = log1pf(fminf((float)TFs[bl], 20.f));
    float idf = 1.f / logf((float)DFs[bl] + 2.f);
    float wt = tf * idf;
    float hv = emb[(size_t)tid * ND + t] * wt;
    int hh = t >> 6, dd = t & 63;
    hw[((size_t)(b * NH + hh) * NL + l) * 64 + dd] = hv;
    float q = hv * hv;
    for (int off = 1; off < 64; off <<= 1) q += __shfl_xor(q, off);
    if (dd == 0) q2[(b * NH + hh) * NL + l] = q;
}

// ---------------- pass A: recompute distances -> BN stats (all heads) ----------------
__global__ __launch_bounds__(256, 2) void distA_kernel(
    const float* __restrict__ hw, const float* __restrict__ q2g, double* __restrict__ stats) {
    __shared__ float As[4096], Bs[4096];
    __shared__ float q2i[64], q2j[64];
    __shared__ float red[8];
    int t = threadIdx.x;
    int bh, i0; decode_blk(blockIdx.x, bh, i0);
    const float* hb = hw + (size_t)bh * (NL * 64);
    const float* q2b = q2g + bh * NL;
    stage_tile(hb + (size_t)i0 * 64, As, t);
    if (t < 64) q2i[t] = q2b[i0 + t];
    int tx = t & 15, ty = t >> 4;
    float lsum = 0.f, lss = 0.f;
    for (int jt = 0; jt < 8; ++jt) {
        __syncthreads();
        stage_tile(hb + (size_t)(jt << 6) * 64, Bs, t);
        if (t < 64) q2j[t] = q2b[(jt << 6) + t];
        __syncthreads();
        float co[4][4];
        dist_tile(As, Bs, q2i, q2j, tx, ty, co);
#pragma unroll
        for (int r = 0; r < 4; ++r)
#pragma unroll
            for (int c = 0; c < 4; ++c) {
                lsum += co[r][c];
                lss += co[r][c] * co[r][c];
            }
    }
    for (int off = 1; off < 64; off <<= 1) {
        lsum += __shfl_xor(lsum, off);
        lss += __shfl_xor(lss, off);
    }
    __syncthreads();
    if ((t & 63) == 0) { red[(t >> 6) * 2] = lsum; red[(t >> 6) * 2 + 1] = lss; }
    __syncthreads();
    if (t == 0) {
        float s = 0.f, ss = 0.f;
        for (int w = 0; w < 4; ++w) { s += red[w * 2]; ss += red[w * 2 + 1]; }
        int h = bh % NH;
        atomicAdd(&stats[h * 2], (double)s);
        atomicAdd(&stats[h * 2 + 1], (double)ss);
    }
}

// ---------------- finalize BN affine for all heads ----------------
__global__ void fin_kernel(const double* __restrict__ stats, const float* __restrict__ gamma,
                           const float* __restrict__ beta, float* __restrict__ bnab) {
    int h = threadIdx.x;
    if (h < NH) {
        double n = (double)NB * NL * NL;
        double mu = stats[h * 2] / n;
        double var = stats[h * 2 + 1] / n - mu * mu;
        double inv = 1.0 / sqrt(var + 1e-5);
        double a = (double)gamma[h] * inv;
        bnab[h * 2] = (float)a;
        bnab[h * 2 + 1] = (float)((double)beta[h] - mu * a);
    }
}

// ---------------- pass B: recompute dist + exp -> PV + row sums (all heads) ----------------
// No-max softmax (BN-standardized scores, f32-safe). K=V: one Bs tile serves both GEMMs.
__global__ __launch_bounds__(256, 2) void distPV_kernel(
    const float* __restrict__ hw, const float* __restrict__ q2g, const int* __restrict__ tids,
    const float* __restrict__ bnab, float* __restrict__ Vcat, float* __restrict__ rowinv) {
    __shared__ float As[4096], Bs[4096], Es[4096];
    __shared__ float q2i[64], q2j[64], rl[64];
    __shared__ int padi[64];
    int t = threadIdx.x;
    int bh, i0; decode_blk(blockIdx.x, bh, i0);
    int b = bh / NH, h = bh % NH;
    float a = bnab[h * 2], bc = bnab[h * 2 + 1];
    const float* hb = hw + (size_t)bh * (NL * 64);
    const float* q2b = q2g + bh * NL;
    stage_tile(hb + (size_t)i0 * 64, As, t);
    if (t < 64) {
        q2i[t] = q2b[i0 + t];
        padi[t] = (tids[(b << 9) + i0 + t] != 0) ? 1 : 0;
    }
    int tx = t & 15, ty = t >> 4;
    float U[4][4] = {};
    float lac[4] = {0.f, 0.f, 0.f, 0.f};
    for (int jt = 0; jt < 8; ++jt) {
        __syncthreads();               // prior Es/Bs consumers done
        stage_tile(hb + (size_t)(jt << 6) * 64, Bs, t);
        if (t < 64) q2j[t] = q2b[(jt << 6) + t];
        __syncthreads();
        float co[4][4];
        dist_tile(As, Bs, q2i, q2j, tx, ty, co);
        int4 tj = *(const int4*)(tids + (b << 9) + (jt << 6) + (tx << 2));
#pragma unroll
        for (int r = 0; r < 4; ++r) {
            int i = ty * 4 + r;
            bool pi = padi[i] != 0;
            float4 e;
            e.x = __expf((pi && tj.x != 0) ? fmaf(a, co[r][0], bc) : 0.f);
            e.y = __expf((pi && tj.y != 0) ? fmaf(a, co[r][1], bc) : 0.f);
            e.z = __expf((pi && tj.z != 0) ? fmaf(a, co[r][2], bc) : 0.f);
            e.w = __expf((pi && tj.w != 0) ? fmaf(a, co[r][3], bc) : 0.f);
            lac[r] += e.x + e.y + e.z + e.w;
            *(float4*)(Es + i * 64 + swz(i, tx << 2)) = e;
        }
        __syncthreads();               // Es ready
        for (int jc = 0; jc < 64; jc += 4) {
            float4 pa[4], vb[4];
#pragma unroll
            for (int r = 0; r < 4; ++r)
                pa[r] = *(const float4*)(Es + (ty * 4 + r) * 64 + swz(ty * 4 + r, jc));
#pragma unroll
            for (int u = 0; u < 4; ++u)
                vb[u] = *(const float4*)(Bs + (jc + u) * 64 + swz(jc + u, tx << 2));
#pragma unroll
            for (int r = 0; r < 4; ++r) {
                U[r][0] += pa[r].x * vb[0].x + pa[r].y * vb[1].x + pa[r].z * vb[2].x + pa[r].w * vb[3].x;
                U[r][1] += pa[r].x * vb[0].y + pa[r].y * vb[1].y + pa[r].z * vb[2].y + pa[r].w * vb[3].y;
                U[r][2] += pa[r].x * vb[0].z + pa[r].y * vb[1].z + pa[r].z * vb[2].z + pa[r].w * vb[3].z;
                U[r][3] += pa[r].x * vb[0].w + pa[r].y * vb[1].w + pa[r].z * vb[2].w + pa[r].w * vb[3].w;
            }
        }
    }
    // row sums over j: reduce across tx lanes (bits 0..3)
#pragma unroll
    for (int r = 0; r < 4; ++r) {
        float s = lac[r];
        s += __shfl_xor(s, 1); s += __shfl_xor(s, 2);
        s += __shfl_xor(s, 4); s += __shfl_xor(s, 8);
        if (tx == 0) {
            float inv = 1.f / s;
            rl[ty * 4 + r] = inv;
            rowinv[(size_t)bh * NL + i0 + ty * 4 + r] = inv;
        }
    }
    __syncthreads();
#pragma unroll
    for (int r = 0; r < 4; ++r) {
        int i = ty * 4 + r;
        float rr = rl[i];
        float4 o;
        o.x = U[r][0] * rr; o.y = U[r][1] * rr; o.z = U[r][2] * rr; o.w = U[r][3] * rr;
        *(float4*)(Vcat + ((size_t)(b << 9) + i0 + i) * ND + h * 64 + (tx << 2)) = o;
    }
}

// ---------------- pass C: recompute dist + exp * (1/l) -> colsum (all heads) ----------------
__global__ __launch_bounds__(256, 2) void colsumC_kernel(
    const float* __restrict__ hw, const float* __restrict__ q2g, const int* __restrict__ tids,
    const float* __restrict__ bnab, const float* __restrict__ rowinv, float* __restrict__ colsum) {
    __shared__ float As[4096], Bs[4096];
    __shared__ float q2i[64], q2j[64], rl[64];
    __shared__ int padi[64];
    __shared__ float csw[4][512];
    int t = threadIdx.x;
    int bh, i0; decode_blk(blockIdx.x, bh, i0);
    int b = bh / NH, h = bh % NH;
    float a = bnab[h * 2], bc = bnab[h * 2 + 1];
    const float* hb = hw + (size_t)bh * (NL * 64);
    const float* q2b = q2g + bh * NL;
    stage_tile(hb + (size_t)i0 * 64, As, t);
    if (t < 64) {
        q2i[t] = q2b[i0 + t];
        padi[t] = (tids[(b << 9) + i0 + t] != 0) ? 1 : 0;
        rl[t] = rowinv[(size_t)bh * NL + i0 + t];
    }
    for (int k = t; k < 2048; k += 256) ((float*)csw)[k] = 0.f;
    int tx = t & 15, ty = t >> 4, wv = t >> 6;
    for (int jt = 0; jt < 8; ++jt) {
        __syncthreads();
        stage_tile(hb + (size_t)(jt << 6) * 64, Bs, t);
        if (t < 64) q2j[t] = q2b[(jt << 6) + t];
        __syncthreads();
        float co[4][4];
        dist_tile(As, Bs, q2i, q2j, tx, ty, co);
        int4 tj = *(const int4*)(tids + (b << 9) + (jt << 6) + (tx << 2));
        float cp0 = 0.f, cp1 = 0.f, cp2 = 0.f, cp3 = 0.f;
#pragma unroll
        for (int r = 0; r < 4; ++r) {
            int i = ty * 4 + r;
            bool pi = padi[i] != 0;
            float rr = rl[i];
            cp0 += __expf((pi && tj.x != 0) ? fmaf(a, co[r][0], bc) : 0.f) * rr;
            cp1 += __expf((pi && tj.y != 0) ? fmaf(a, co[r][1], bc) : 0.f) * rr;
            cp2 += __expf((pi && tj.z != 0) ? fmaf(a, co[r][2], bc) : 0.f) * rr;
            cp3 += __expf((pi && tj.w != 0) ? fmaf(a, co[r][3], bc) : 0.f) * rr;
        }
        cp0 += __shfl_xor(cp0, 16); cp0 += __shfl_xor(cp0, 32);
        cp1 += __shfl_xor(cp1, 16); cp1 += __shfl_xor(cp1, 32);
        cp2 += __shfl_xor(cp2, 16); cp2 += __shfl_xor(cp2, 32);
        cp3 += __shfl_xor(cp3, 16); cp3 += __shfl_xor(cp3, 32);
        if ((t & 48) == 0) {           // one ty-group per wave holds the wave partial
            int j = (jt << 6) + (tx << 2);
            csw[wv][j + 0] += cp0;
            csw[wv][j + 1] += cp1;
            csw[wv][j + 2] += cp2;
            csw[wv][j + 3] += cp3;
        }
    }
    __syncthreads();
    for (int k = t; k < 512; k += 256) {
        float s = csw[0][k] + csw[1][k] + csw[2][k] + csw[3][k];
        atomicAdd(&colsum[(size_t)bh * NL + k], s);
    }
}

// ---------------- token-weight softmax w[b,l] ----------------
__global__ __launch_bounds__(512) void wk_kernel(
    const int* __restrict__ tids, const float* __restrict__ colsum, float* __restrict__ wvec) {
    __shared__ float red[8];
    __shared__ int redi[8];
    int b = blockIdx.x, l = threadIdx.x;
    int lane = l & 63, wv = l >> 6;
    int padv = (tids[(b << 9) + l] != 0) ? 1 : 0;
    int cnt = padv;
    for (int off = 1; off < 64; off <<= 1) cnt += __shfl_xor(cnt, off);
    if (lane == 0) redi[wv] = cnt;
    __syncthreads();
    int ds = 0;
    for (int k = 0; k < 8; ++k) ds += redi[k];
    if (ds < 1) ds = 1;
    float cs = 0.f;
    for (int hh = 0; hh < NH; ++hh) cs += colsum[(size_t)(b * NH + hh) * NL + l];
    float x = padv ? cs / (6.f * (float)ds) : -INFINITY;
    float m = x;
    for (int off = 1; off < 64; off <<= 1) m = fmaxf(m, __shfl_xor(m, off));
    if (lane == 0) red[wv] = m;
    __syncthreads();
    float bm = red[0];
    for (int k = 1; k < 8; ++k) bm = fmaxf(bm, red[k]);
    float e = padv ? __expf(x - bm) : 0.f;
    float se = e;
    for (int off = 1; off < 64; off <<= 1) se += __shfl_xor(se, off);
    __syncthreads();
    if (lane == 0) red[wv] = se;
    __syncthreads();
    float total = 0.f;
    for (int k = 0; k < 8; ++k) total += red[k];
    wvec[(b << 9) + l] = (total > 0.f) ? e / total : 0.f;
}

// ---------------- fc + per-token softmax + weighted sum ----------------
__global__ __launch_bounds__(256) void logits_kernel(
    const float* __restrict__ Vcat, const float* __restrict__ fcw, const float* __restrict__ fcb,
    const float* __restrict__ wvec, float* __restrict__ lacc) {
    __shared__ float red[4][64];
    int t = threadIdx.x;
    int wv = t >> 6, lane = t & 63;
    int tok0 = (blockIdx.x * 4 + wv) * 4;    // 16 consecutive tokens per block
    int b = tok0 >> 9;                       // all 16 in the same batch row
    int wrow = (lane < NCP) ? lane : (NCP - 1);
    const float* wp = fcw + wrow * ND;
    const float* vp = Vcat + (size_t)tok0 * ND;
    float acc0 = 0.f, acc1 = 0.f, acc2 = 0.f, acc3 = 0.f;
#pragma unroll 2
    for (int kc = 0; kc < ND; kc += 4) {
        float4 w4 = *(const float4*)(wp + kc);
        float4 v0 = *(const float4*)(vp + kc);
        float4 v1 = *(const float4*)(vp + ND + kc);
        float4 v2 = *(const float4*)(vp + 2 * ND + kc);
        float4 v3 = *(const float4*)(vp + 3 * ND + kc);
        acc0 += v0.x * w4.x + v0.y * w4.y + v0.z * w4.z + v0.w * w4.w;
        acc1 += v1.x * w4.x + v1.y * w4.y + v1.z * w4.z + v1.w * w4.w;
        acc2 += v2.x * w4.x + v2.y * w4.y + v2.z * w4.z + v2.w * w4.w;
        acc3 += v3.x * w4.x + v3.y * w4.y + v3.z * w4.z + v3.w * w4.w;
    }
    float bias = fcb[wrow];
    float g[4] = {acc0 + bias, acc1 + bias, acc2 + bias, acc3 + bias};
    float lsum = 0.f;
#pragma unroll
    for (int u = 0; u < 4; ++u) {
        float gm = (lane < NCP) ? g[u] : -INFINITY;
        float m = gm;
        for (int off = 1; off < 64; off <<= 1) m = fmaxf(m, __shfl_xor(m, off));
        float e = (lane < NCP) ? __expf(g[u] - m) : 0.f;
        float s = e;
        for (int off = 1; off < 64; off <<= 1) s += __shfl_xor(s, off);
        lsum += (e / s) * wvec[tok0 + u];
    }
    red[wv][lane] = lsum;
    __syncthreads();
    if (wv == 0) {
        float tot = red[0][lane] + red[1][lane] + red[2][lane] + red[3][lane];
        if (lane < NCP) atomicAdd(&lacc[b * NCP + lane], tot);
    }
}

// ---------------- final softmax over first 50 ----------------
__global__ __launch_bounds__(64) void final_kernel(const float* __restrict__ lacc, float* __restrict__ out) {
    int b = blockIdx.x, lane = threadIdx.x;
    float x = (lane < NC) ? lacc[b * NCP + lane] : -INFINITY;
    float m = x;
    for (int off = 1; off < 64; off <<= 1) m = fmaxf(m, __shfl_xor(m, off));
    float e = (lane < NC) ? __expf(x - m) : 0.f;
    float s = e;
    for (int off = 1; off < 64; off <<= 1) s += __shfl_xor(s, off);
    if (lane < NC) out[b * NC + lane] = e / s;
}

extern "C" void kernel_launch(void* const* d_in, const int* in_sizes, int n_in,
                              void* d_out, int out_size, void* d_ws, size_t ws_size,
                              hipStream_t stream) {
    const int* tids = (const int*)d_in[0];
    const int* TFs = (const int*)d_in[1];
    const int* DFs = (const int*)d_in[2];
    const float* emb = (const float*)d_in[3];
    const float* gamma = (const float*)d_in[4];
    const float* beta = (const float*)d_in[5];
    const float* fcw = (const float*)d_in[6];
    const float* fcb = (const float*)d_in[7];
    float* out = (float*)d_out;

    char* ws = (char*)d_ws;
    float* hw = (float*)ws;                              // 25,165,824 B
    float* q2 = (float*)(ws + 25165824);                 //    393,216 B
    float* Vcat = (float*)(ws + 25559040);               // 25,165,824 B
    float* rowinv = (float*)(ws + 50724864);             //    393,216 B
    char* zbase = ws + 51118080;                         //    400,000 B zero region
    double* stats = (double*)zbase;                      // 12 doubles (pad 128)
    float* colsum = (float*)(zbase + 128);               //    393,216 B
    float* lacc = (float*)(zbase + 128 + 393216);        //      6,656 B
    float* bnab = (float*)(ws + 51518080);               //         48 B
    float* wvec = (float*)(ws + 51518144);               //     65,536 B

    zero_kernel<<<64, 256, 0, stream>>>((float4*)zbase);
    embed_kernel<<<NB * NL, ND, 0, stream>>>(tids, TFs, DFs, emb, hw, q2);
    distA_kernel<<<NBH * 8, 256, 0, stream>>>(hw, q2, stats);
    fin_kernel<<<1, 64, 0, stream>>>(stats, gamma, beta, bnab);
    distPV_kernel<<<NBH * 8, 256, 0, stream>>>(hw, q2, tids, bnab, Vcat, rowinv);
    colsumC_kernel<<<NBH * 8, 256, 0, stream>>>(hw, q2, tids, bnab, rowinv, colsum);
    wk_kernel<<<NB, 512, 0, stream>>>(tids, colsum, wvec);
    logits_kernel<<<NB * 4, 256, 0, stream>>>(Vcat, fcw, fcb, wvec, lacc);
    final_kernel<<<NB, 64, 0, stream>>>(lacc, out);
}